// Round 5
// baseline (204.662 us; speedup 1.0000x reference)
//
#include <hip/hip_runtime.h>

#define BATCH 4
#define NPTS  2048
#define DZDIM 128
#define GD    128
#define M_TOT (GD*GD)
#define TN    32
#define ZP    2112      // zt/xs row pitch (elements): 2048 data + 64 zeroed tail, 16B-aligned
#define WBIN  15        // +-15 bins: w < 7e-6 outside

typedef __attribute__((ext_vector_type(8))) __bf16 bf16x8;
typedef __attribute__((ext_vector_type(4))) float floatx4;
typedef __attribute__((ext_vector_type(4))) unsigned int uintx4;

__device__ __forceinline__ unsigned int f2bf_bits(float x){
  unsigned int u = __float_as_uint(x);
  u += 0x7FFFu + ((u >> 16) & 1u);
  return u >> 16;
}
__device__ __forceinline__ int point_bin(float px){
  int bin = __float2int_rn((px + 2.0f) * (127.0f / 4.0f));
  return min(GD - 1, max(0, bin));
}

// ---- prep: hist+scan (blocks 0..3) | x_grid bcast (4..131) | xs/zt tail zero (132..134) ----
__global__ __launch_bounds__(256) void prep_kernel(
    const float* __restrict__ x, const float* __restrict__ grid,
    float* __restrict__ out, int* __restrict__ binStart,
    float2* __restrict__ xs, unsigned short* __restrict__ zt)
{
  const int tid = threadIdx.x;
  const int bx  = blockIdx.x;
  if (bx < BATCH){
    __shared__ int h[GD];
    __shared__ int s[GD + 1];
    const int b = bx;
    if (tid < GD) h[tid] = 0;
    __syncthreads();
    for (int n = tid; n < NPTS; n += 256)
      atomicAdd(&h[point_bin(x[(b*NPTS + n)*2])], 1);
    __syncthreads();
    if (tid == 0){
      int acc = 0;
#pragma unroll
      for (int j = 0; j < GD; ++j){ s[j] = acc; acc += h[j]; }
      s[GD] = acc;
    }
    __syncthreads();
    if (tid <= GD) binStart[b*(GD+1) + tid] = s[tid];
  } else if (bx < BATCH + 128){
    int idx = (bx - BATCH) * 256 + tid;       // 0..32767 == GD*GD*2
    float g = grid[idx];
#pragma unroll
    for (int b = 0; b < BATCH; ++b) out[b*(GD*GD*2) + idx] = g;
  } else if (bx == BATCH + 128){
    // xs tail: 4 batches x 64 float2 -> (0,0)
    int b = tid >> 6, j = tid & 63;
    xs[(size_t)b*ZP + NPTS + j] = make_float2(0.f, 0.f);
  } else {
    // zt tail: 512 rows x 128 B -> 0 ; 2 blocks x 256 rows
    int row = (bx - (BATCH + 129)) * 256 + tid;   // 0..511 == b*128+dz
    uintx4 zv = {0u, 0u, 0u, 0u};
    uintx4* p = (uintx4*)&zt[(size_t)row*ZP + NPTS];
#pragma unroll
    for (int c = 0; c < 8; ++c) p[c] = zv;
  }
}

// ---- stable (index-order) scatter into bin-sorted arrays: xs (float2) + perm ----
__global__ __launch_bounds__(256) void scatter_kernel(const float* __restrict__ x,
                                                      const int* __restrict__ binStart,
                                                      float2* __restrict__ xs,
                                                      int* __restrict__ perm){
  const int b = blockIdx.y;
  const int wv = threadIdx.x >> 6, lane = threadIdx.x & 63;
  const int bin = blockIdx.x * 4 + wv;    // one wave per bin
  int base = binStart[b*(GD+1) + bin];
  const float2* __restrict__ x2 = (const float2*)x;
  for (int n0 = 0; n0 < NPTS; n0 += 64){
    int n = n0 + lane;
    float2 xv = x2[b*NPTS + n];
    bool keep = (point_bin(xv.x) == bin);
    unsigned long long mask = __ballot(keep);
    int pre = __popcll(mask & ((1ull << lane) - 1ull));
    if (keep){
      xs[(long)b*ZP + base + pre] = xv;
      perm[b*NPTS + base + pre]   = n;
    }
    base += __popcll(mask);
  }
}

// ---- zt[b][dz][j] = bf16(z[b][perm[j]][dz]); 256 blocks (dz halved) for full-CU fill ----
__global__ __launch_bounds__(256) void ztbuild_kernel(const float* __restrict__ z,
                                                      const int* __restrict__ perm,
                                                      unsigned short* __restrict__ zt){
  const int by = blockIdx.y;             // b*2 + half
  const int b = by >> 1, half = by & 1;
  const int j0 = blockIdx.x * 64;
  const int jj = threadIdx.x & 63;       // consecutive lanes -> consecutive j (coalesced)
  const int dq = threadIdx.x >> 6;       // 0..3
  const int j  = j0 + jj;
  const int n  = perm[b*NPTS + j];
  const float4* __restrict__ z4 = (const float4*)z;
  const long rb = (long)(b*NPTS + n) * 32;
#pragma unroll
  for (int r = 0; r < 4; ++r){
    int c = half*16 + dq*4 + r;          // float4 chunk -> dz = 4c..4c+3
    float4 v = z4[rb + c];
    long o = ((long)(b*DZDIM + 4*c) * ZP) + j;
    zt[o        ] = (unsigned short)f2bf_bits(v.x);
    zt[o +   ZP ] = (unsigned short)f2bf_bits(v.y);
    zt[o + 2*ZP ] = (unsigned short)f2bf_bits(v.z);
    zt[o + 3*ZP ] = (unsigned short)f2bf_bits(v.w);
  }
}

// ---- main: NO LDS, NO barriers. A generated in-register, B straight from L1/L2. ----
// block = (b, row i, m-half); wave covers 16 m x 128 dz; reg-double-buffered B.
__global__ __launch_bounds__(256, 4) void setconv_mfma_kernel(
    const float2* __restrict__ xs, const int* __restrict__ binStart,
    const unsigned short* __restrict__ zt, const float* __restrict__ lsp,
    float* __restrict__ outz)
{
  const int tid = threadIdx.x, lane = tid & 63, wv = tid >> 6;
  const int bid = blockIdx.x;
  const int g   = bid & 7;               // XCD band: g owns rows [16g,16g+16)
  const int s   = bid >> 3;
  const int h   = s & 1;
  const int b   = (s >> 1) & 3;
  const int il  = s >> 3;
  const int i   = g*16 + il;
  const int my0 = h * 64;

  const float l0 = 1e-5f + log1pf(expf(lsp[0]));
  const float l1 = 1e-5f + log1pf(expf(lsp[1]));
  const float LOG2E = 1.4426950408889634f;
  const float c0 = -0.5f * LOG2E / (l0*l0);
  const float c1 = -0.5f * LOG2E / (l1*l1);
  const float step = 4.0f / 127.0f;
  const float gx   = -2.0f + (float)i * step;

  const int lo   = binStart[b*(GD+1) + max(0, i - WBIN)];
  const int hi   = binStart[b*(GD+1) + min(GD-1, i + WBIN) + 1];
  const int lo32 = lo & ~31;             // 64B-align k-base; extras get true tiny w
  const int T    = (hi - lo32 + TN - 1) / TN;

  const int q  = lane >> 4, ml = lane & 15;
  const int m  = my0 + wv*16 + ml;       // lane's A-row
  const float gym = -2.0f + (float)m * step;

  const unsigned short* __restrict__ ztb = zt + ((size_t)b*DZDIM + ml)*ZP;
  const float4* __restrict__ xsb = (const float4*)(xs + (size_t)b*ZP);

  floatx4 acc[8];
#pragma unroll
  for (int tz = 0; tz < 8; ++tz) acc[tz] = (floatx4){0.f, 0.f, 0.f, 0.f};

  bf16x8 Ba[8], Bb[8];

  auto loadB = [&](bf16x8* dst, int t){
    const int k = lo32 + t*TN + q*8;
#pragma unroll
    for (int tz = 0; tz < 8; ++tz)       // 16 rows x 64B fully-consumed lines per instr
      dst[tz] = *(const bf16x8*)&ztb[(size_t)(tz*16)*ZP + k];
  };
  auto stepT = [&](const bf16x8* curB, int t){
    const int kp = lo32 + t*TN + q*8;    // lane's 8 k-points
    float4 P0 = xsb[(kp >> 1)    ];
    float4 P1 = xsb[(kp >> 1) + 1];
    float4 P2 = xsb[(kp >> 1) + 2];
    float4 P3 = xsb[(kp >> 1) + 3];
    float px[8] = {P0.x,P0.z,P1.x,P1.z,P2.x,P2.z,P3.x,P3.z};
    float py[8] = {P0.y,P0.w,P1.y,P1.w,P2.y,P2.w,P3.y,P3.w};
    unsigned int u[4];
#pragma unroll
    for (int p = 0; p < 4; ++p){
      float dx0 = gx - px[2*p],   t00 = (c0*dx0)*dx0;
      float dy0 = gym - py[2*p];
      float w0  = __builtin_amdgcn_exp2f(fmaf(c1*dy0, dy0, t00));
      float dx1 = gx - px[2*p+1], t01 = (c0*dx1)*dx1;
      float dy1 = gym - py[2*p+1];
      float w1  = __builtin_amdgcn_exp2f(fmaf(c1*dy1, dy1, t01));
      u[p] = f2bf_bits(w0) | (f2bf_bits(w1) << 16);
    }
    union { uintx4 u4; bf16x8 v; } cvt;
    cvt.u4 = (uintx4){u[0], u[1], u[2], u[3]};
    bf16x8 af = cvt.v;
#pragma unroll
    for (int tz = 0; tz < 8; ++tz)
      acc[tz] = __builtin_amdgcn_mfma_f32_16x16x32_bf16(af, curB[tz], acc[tz], 0, 0, 0);
  };

  if (T > 0){
    loadB(Ba, 0);
    int t = 0;
    while (true){
      if (t + 1 < T) loadB(Bb, t + 1);   // loads fly during A-gen + MFMA below
      stepT(Ba, t);
      ++t; if (t >= T) break;
      if (t + 1 < T) loadB(Ba, t + 1);
      stepT(Bb, t);
      ++t; if (t >= T) break;
    }
  }

  // epilogue: C/D col(dz)=ml, row(m)=q*4+r
  const size_t obase = ((size_t)(b*M_TOT + i*GD + my0 + wv*16 + q*4) << 7) + ml;
#pragma unroll
  for (int tz = 0; tz < 8; ++tz)
#pragma unroll
    for (int r = 0; r < 4; ++r)
      outz[obase + ((size_t)r << 7) + tz*16] = acc[tz][r];
}

extern "C" void kernel_launch(void* const* d_in, const int* in_sizes, int n_in,
                              void* d_out, int out_size, void* d_ws, size_t ws_size,
                              hipStream_t stream)
{
  const float* x    = (const float*)d_in[0];
  const float* z    = (const float*)d_in[1];
  const float* grid = (const float*)d_in[2];
  const float* lsp  = (const float*)d_in[3];
  float* out = (float*)d_out;

  char* ws = (char*)d_ws;
  int*            binStart = (int*)ws;                       // 2064 B
  int*            perm     = (int*)(ws + 2064);              // 32768 B
  float2*         xs       = (float2*)(ws + 2064 + 32768);   // 67584 B (16B-aligned)
  unsigned short* zt       = (unsigned short*)(ws + 2064 + 32768 + 67584); // 2.16 MB

  hipLaunchKernelGGL(prep_kernel, dim3(BATCH + 128 + 3), dim3(256), 0, stream,
                     x, grid, out, binStart, xs, zt);
  hipLaunchKernelGGL(scatter_kernel, dim3(GD/4, BATCH), dim3(256), 0, stream,
                     x, binStart, xs, perm);
  hipLaunchKernelGGL(ztbuild_kernel, dim3(NPTS/64, BATCH*2), dim3(256), 0, stream,
                     z, perm, zt);
  hipLaunchKernelGGL(setconv_mfma_kernel, dim3(GD*2*BATCH), dim3(256), 0, stream,
                     xs, binStart, zt, lsp, out + BATCH*GD*GD*2);
}

// Round 6
// 127.124 us; speedup vs baseline: 1.6099x; 1.6099x over previous
//
#include <hip/hip_runtime.h>

#define BATCH 4
#define NPTS  2048
#define DZDIM 128
#define GD    128
#define M_TOT (GD*GD)
#define TN    32
#define ZP    2112      // zt/xs row pitch (elements): 2048 data + 64 zeroed tail, 16B-aligned
#define WBIN  15        // +-15 bins: w < 7e-6 outside

typedef __attribute__((ext_vector_type(8))) __bf16 bf16x8;
typedef __attribute__((ext_vector_type(4))) float floatx4;
typedef __attribute__((ext_vector_type(4))) unsigned int uintx4;

__device__ __forceinline__ unsigned int f2bf_bits(float x){
  unsigned int u = __float_as_uint(x);
  u += 0x7FFFu + ((u >> 16) & 1u);
  return u >> 16;
}
__device__ __forceinline__ int point_bin(float px){
  int bin = __float2int_rn((px + 2.0f) * (127.0f / 4.0f));
  return min(GD - 1, max(0, bin));
}

// ---- prep: hist+scan (blocks 0..3) | x_grid bcast (4..131) | xs/zt tail zero (132..134) ----
__global__ __launch_bounds__(256) void prep_kernel(
    const float* __restrict__ x, const float* __restrict__ grid,
    float* __restrict__ out, int* __restrict__ binStart,
    float2* __restrict__ xs, unsigned short* __restrict__ zt)
{
  const int tid = threadIdx.x;
  const int bx  = blockIdx.x;
  if (bx < BATCH){
    __shared__ int h[GD];
    __shared__ int s[GD + 1];
    const int b = bx;
    if (tid < GD) h[tid] = 0;
    __syncthreads();
    for (int n = tid; n < NPTS; n += 256)
      atomicAdd(&h[point_bin(x[(b*NPTS + n)*2])], 1);
    __syncthreads();
    if (tid == 0){
      int acc = 0;
#pragma unroll
      for (int j = 0; j < GD; ++j){ s[j] = acc; acc += h[j]; }
      s[GD] = acc;
    }
    __syncthreads();
    if (tid <= GD) binStart[b*(GD+1) + tid] = s[tid];
  } else if (bx < BATCH + 128){
    int idx = (bx - BATCH) * 256 + tid;       // 0..32767 == GD*GD*2
    float g = grid[idx];
#pragma unroll
    for (int b = 0; b < BATCH; ++b) out[b*(GD*GD*2) + idx] = g;
  } else if (bx == BATCH + 128){
    // xs tail: 4 batches x 64 float2 -> (0,0)  (weights vs (0,0) are multiplied by zt==0)
    int b = tid >> 6, j = tid & 63;
    xs[(size_t)b*ZP + NPTS + j] = make_float2(0.f, 0.f);
  } else {
    // zt tail: 512 rows x 128 B -> 0 ; 2 blocks x 256 rows
    int row = (bx - (BATCH + 129)) * 256 + tid;   // 0..511 == b*128+dz
    uintx4 zv = {0u, 0u, 0u, 0u};
    uintx4* p = (uintx4*)&zt[(size_t)row*ZP + NPTS];
#pragma unroll
    for (int c = 0; c < 8; ++c) p[c] = zv;
  }
}

// ---- stable (index-order) scatter into bin-sorted arrays: xs (float2) + perm ----
__global__ __launch_bounds__(256) void scatter_kernel(const float* __restrict__ x,
                                                      const int* __restrict__ binStart,
                                                      float2* __restrict__ xs,
                                                      int* __restrict__ perm){
  const int b = blockIdx.y;
  const int wv = threadIdx.x >> 6, lane = threadIdx.x & 63;
  const int bin = blockIdx.x * 4 + wv;    // one wave per bin
  int base = binStart[b*(GD+1) + bin];
  const float2* __restrict__ x2 = (const float2*)x;
  for (int n0 = 0; n0 < NPTS; n0 += 64){
    int n = n0 + lane;
    float2 xv = x2[b*NPTS + n];
    bool keep = (point_bin(xv.x) == bin);
    unsigned long long mask = __ballot(keep);
    int pre = __popcll(mask & ((1ull << lane) - 1ull));
    if (keep){
      xs[(long)b*ZP + base + pre] = xv;
      perm[b*NPTS + base + pre]   = n;
    }
    base += __popcll(mask);
  }
}

// ---- zt[b][dz][j] = bf16(z[b][perm[j]][dz]) ----
__global__ __launch_bounds__(256) void ztbuild_kernel(const float* __restrict__ z,
                                                      const int* __restrict__ perm,
                                                      unsigned short* __restrict__ zt){
  const int by = blockIdx.y;             // b*2 + half
  const int b = by >> 1, half = by & 1;
  const int j0 = blockIdx.x * 64;
  const int jj = threadIdx.x & 63;       // consecutive lanes -> consecutive j (coalesced)
  const int dq = threadIdx.x >> 6;       // 0..3
  const int j  = j0 + jj;
  const int n  = perm[b*NPTS + j];
  const float4* __restrict__ z4 = (const float4*)z;
  const long rb = (long)(b*NPTS + n) * 32;
#pragma unroll
  for (int r = 0; r < 4; ++r){
    int c = half*16 + dq*4 + r;          // float4 chunk -> dz = 4c..4c+3
    float4 v = z4[rb + c];
    long o = ((long)(b*DZDIM + 4*c) * ZP) + j;
    zt[o        ] = (unsigned short)f2bf_bits(v.x);
    zt[o +   ZP ] = (unsigned short)f2bf_bits(v.y);
    zt[o + 2*ZP ] = (unsigned short)f2bf_bits(v.z);
    zt[o + 3*ZP ] = (unsigned short)f2bf_bits(v.w);
  }
}

// ---- main: NO LDS, NO barriers. block = one (b, grid-row i) = 128m x 128dz.
// wave = 32m x 128dz (two A-frags share each B-load); B reg-double-buffered.
// launch_bounds(256,2): 256 unified VGPRs/wave -- R5's (256,4) caused scratch spill.
__global__ __launch_bounds__(256, 2) void setconv_mfma_kernel(
    const float2* __restrict__ xs, const int* __restrict__ binStart,
    const unsigned short* __restrict__ zt, const float* __restrict__ lsp,
    float* __restrict__ outz)
{
  const int tid = threadIdx.x, lane = tid & 63, wv = tid >> 6;
  const int bid = blockIdx.x;            // 512 blocks
  const int g   = bid & 7;               // XCD band: g owns rows [16g,16g+16)
  const int s   = bid >> 3;              // 0..63
  const int b   = s & 3;
  const int il  = s >> 2;                // 0..15
  const int i   = g*16 + il;

  const float l0 = 1e-5f + log1pf(expf(lsp[0]));
  const float l1 = 1e-5f + log1pf(expf(lsp[1]));
  const float LOG2E = 1.4426950408889634f;
  const float c0 = -0.5f * LOG2E / (l0*l0);
  const float c1 = -0.5f * LOG2E / (l1*l1);
  const float step = 4.0f / 127.0f;
  const float gx   = -2.0f + (float)i * step;

  const int lo   = binStart[b*(GD+1) + max(0, i - WBIN)];
  const int hi   = binStart[b*(GD+1) + min(GD-1, i + WBIN) + 1];
  const int lo32 = lo & ~31;             // 64B-align k-base; extras get true tiny w
  const int T    = (hi - lo32 + TN - 1) / TN;

  const int q  = lane >> 4, ml = lane & 15;
  const int m0 = wv*32 + ml;             // A-frag 0 row
  const float gym0 = -2.0f + (float)m0 * step;
  const float gym1 = gym0 + 16.0f * step;   // A-frag 1 row (m0+16)

  const unsigned short* __restrict__ ztb = zt + ((size_t)b*DZDIM + ml)*ZP;
  const float4* __restrict__ xsb = (const float4*)(xs + (size_t)b*ZP);

  floatx4 acc0[8], acc1[8];
#pragma unroll
  for (int tz = 0; tz < 8; ++tz){
    acc0[tz] = (floatx4){0.f, 0.f, 0.f, 0.f};
    acc1[tz] = (floatx4){0.f, 0.f, 0.f, 0.f};
  }

  bf16x8 Ba[8], Bb[8];

  auto loadB = [&](bf16x8* dst, int t){
    const int k = lo32 + t*TN + q*8;
#pragma unroll
    for (int tz = 0; tz < 8; ++tz)       // 16 lanes x 64B consecutive rows per instr
      dst[tz] = *(const bf16x8*)&ztb[(size_t)(tz*16)*ZP + k];
  };
  auto stepT = [&](const bf16x8* curB, int t){
    const int kp = lo32 + t*TN + q*8;    // lane's 8 k-points
    float4 P0 = xsb[(kp >> 1)    ];
    float4 P1 = xsb[(kp >> 1) + 1];
    float4 P2 = xsb[(kp >> 1) + 2];
    float4 P3 = xsb[(kp >> 1) + 3];
    float px[8] = {P0.x,P0.z,P1.x,P1.z,P2.x,P2.z,P3.x,P3.z};
    float py[8] = {P0.y,P0.w,P1.y,P1.w,P2.y,P2.w,P3.y,P3.w};
    unsigned int u0[4], u1[4];
#pragma unroll
    for (int p = 0; p < 4; ++p){
      float w0[2], w1[2];
#pragma unroll
      for (int e = 0; e < 2; ++e){
        float dx = gx - px[2*p + e];
        float t0 = (c0*dx)*dx;           // shared across both m-frags
        float dy0 = gym0 - py[2*p + e];
        float dy1 = gym1 - py[2*p + e];
        w0[e] = __builtin_amdgcn_exp2f(fmaf(c1*dy0, dy0, t0));
        w1[e] = __builtin_amdgcn_exp2f(fmaf(c1*dy1, dy1, t0));
      }
      u0[p] = f2bf_bits(w0[0]) | (f2bf_bits(w0[1]) << 16);
      u1[p] = f2bf_bits(w1[0]) | (f2bf_bits(w1[1]) << 16);
    }
    union { uintx4 u4; bf16x8 v; } cv0, cv1;
    cv0.u4 = (uintx4){u0[0], u0[1], u0[2], u0[3]};
    cv1.u4 = (uintx4){u1[0], u1[1], u1[2], u1[3]};
    bf16x8 af0 = cv0.v, af1 = cv1.v;
#pragma unroll
    for (int tz = 0; tz < 8; ++tz){
      acc0[tz] = __builtin_amdgcn_mfma_f32_16x16x32_bf16(af0, curB[tz], acc0[tz], 0, 0, 0);
      acc1[tz] = __builtin_amdgcn_mfma_f32_16x16x32_bf16(af1, curB[tz], acc1[tz], 0, 0, 0);
    }
  };

  if (T > 0){
    loadB(Ba, 0);
    int t = 0;
    while (true){
      if (t + 1 < T) loadB(Bb, t + 1);   // loads fly during A-gen + MFMA below
      stepT(Ba, t);
      ++t; if (t >= T) break;
      if (t + 1 < T) loadB(Ba, t + 1);
      stepT(Bb, t);
      ++t; if (t >= T) break;
    }
  }

  // epilogue: C/D col(dz)=ml, row(m)=q*4+r ; frag1 rows +16
  const size_t ob0 = ((size_t)(b*M_TOT + i*GD + wv*32 + q*4) << 7) + ml;
#pragma unroll
  for (int tz = 0; tz < 8; ++tz)
#pragma unroll
    for (int r = 0; r < 4; ++r){
      outz[ob0 + ((size_t)r << 7) + tz*16]            = acc0[tz][r];
      outz[ob0 + ((size_t)(r + 16) << 7) + tz*16]     = acc1[tz][r];
    }
}

extern "C" void kernel_launch(void* const* d_in, const int* in_sizes, int n_in,
                              void* d_out, int out_size, void* d_ws, size_t ws_size,
                              hipStream_t stream)
{
  const float* x    = (const float*)d_in[0];
  const float* z    = (const float*)d_in[1];
  const float* grid = (const float*)d_in[2];
  const float* lsp  = (const float*)d_in[3];
  float* out = (float*)d_out;

  char* ws = (char*)d_ws;
  int*            binStart = (int*)ws;                       // 2064 B
  int*            perm     = (int*)(ws + 2064);              // 32768 B
  float2*         xs       = (float2*)(ws + 2064 + 32768);   // 67584 B (16B-aligned)
  unsigned short* zt       = (unsigned short*)(ws + 2064 + 32768 + 67584); // 2.16 MB

  hipLaunchKernelGGL(prep_kernel, dim3(BATCH + 128 + 3), dim3(256), 0, stream,
                     x, grid, out, binStart, xs, zt);
  hipLaunchKernelGGL(scatter_kernel, dim3(GD/4, BATCH), dim3(256), 0, stream,
                     x, binStart, xs, perm);
  hipLaunchKernelGGL(ztbuild_kernel, dim3(NPTS/64, BATCH*2), dim3(256), 0, stream,
                     z, perm, zt);
  hipLaunchKernelGGL(setconv_mfma_kernel, dim3(GD*BATCH), dim3(256), 0, stream,
                     xs, binStart, zt, lsp, out + BATCH*GD*GD*2);
}